// Round 1
// baseline (495.096 us; speedup 1.0000x reference)
//
#include <hip/hip_runtime.h>

#define NNODES 100000
#define NEDGES 1600000
#define FDIM 128
#define EDIM 32
#define NCLS 17
#define ROWU 32   // per-node row = 32 u32 = 128 B = 2 cachelines:
                  // u32[0..15]  : embed as 32 x bf16 (packed pairs)
                  // u32[16..24] : h = 0.5*lin + sq as 17 x bf16 (packed pairs)
#define BCAP 64   // bucket capacity per node; deg ~ Poisson(16), P(deg>=64) ~ 1e-18

typedef unsigned int u32;

__device__ inline u32 bf16r(float x) {            // round-to-nearest-even bf16
  u32 u = __float_as_uint(x);
  return (u + 0x7FFFu + ((u >> 16) & 1u)) >> 16;
}
__device__ inline u32 pk(float lo, float hi) { return bf16r(lo) | (bf16r(hi) << 16); }
__device__ inline float lo16(u32 u) { return __uint_as_float(u << 16); }
__device__ inline float hi16(u32 u) { return __uint_as_float(u & 0xFFFF0000u); }

// ---------------- Kernel A: per-node embed + h, thread = node, no LDS ----------------
__global__ __launch_bounds__(256) void node_kernel(
    const float* __restrict__ features,
    const float* __restrict__ W_embed,   // [128][32]
    const float* __restrict__ b_embed,   // [32]
    const float* __restrict__ W_trans,   // [64][17]
    u32* __restrict__ nodetab)
{
  int n = blockIdx.x * 256 + threadIdx.x;
  if (n >= NNODES) return;

  float acc[EDIM];
  #pragma unroll
  for (int c = 0; c < EDIM; ++c) acc[c] = b_embed[c];

  const float4* f4 = (const float4*)(features + (size_t)n * FDIM);
  for (int k4 = 0; k4 < FDIM / 4; ++k4) {
    float4 f = f4[k4];
    const float* w = W_embed + k4 * 4 * EDIM;   // uniform -> s_load
    #pragma unroll
    for (int c = 0; c < EDIM; ++c) {
      acc[c] = fmaf(f.x, w[c],            acc[c]);
      acc[c] = fmaf(f.y, w[EDIM + c],     acc[c]);
      acc[c] = fmaf(f.z, w[2 * EDIM + c], acc[c]);
      acc[c] = fmaf(f.w, w[3 * EDIM + c], acc[c]);
    }
  }

  float sq[EDIM];
  #pragma unroll
  for (int k = 0; k < EDIM; ++k) sq[k] = acc[k] * acc[k];

  float h[NCLS + 1];
  #pragma unroll
  for (int c = 0; c < NCLS; ++c) {
    float lin = 0.f, sqs = 0.f;
    #pragma unroll
    for (int k = 0; k < EDIM; ++k) {
      lin = fmaf(acc[k], W_trans[k * NCLS + c],          lin);
      sqs = fmaf(sq[k],  W_trans[(EDIM + k) * NCLS + c], sqs);
    }
    h[c] = 0.5f * lin + sqs;
  }
  h[NCLS] = 0.f;

  u32* row = nodetab + (size_t)n * ROWU;
  u32 p[16];
  #pragma unroll
  for (int i = 0; i < 16; ++i) p[i] = pk(acc[2 * i], acc[2 * i + 1]);
  #pragma unroll
  for (int i = 0; i < 4; ++i)
    ((uint4*)row)[i] = make_uint4(p[4 * i], p[4 * i + 1], p[4 * i + 2], p[4 * i + 3]);
  #pragma unroll
  for (int i = 0; i < 9; ++i) row[16 + i] = pk(h[2 * i], h[2 * i + 1]);
}

// ---------------- Kernel B (fast): per-edge softmax; scatter only a bucket id ----------------
// Replaces 17 fp32 memory-side atomic RMWs per edge (≈192 B beyond-L2 traffic each)
// with ONE u32 atomic + one 4 B scatter. The segment-sum becomes a gather (Kernel R).
__global__ __launch_bounds__(256, 4) void edge_kernel_fast(
    const int*   __restrict__ edges,
    const float* __restrict__ W_trans,
    const float* __restrict__ b_trans,
    const u32*   __restrict__ nodetab,
    float* __restrict__ poss_edge,
    u32*   __restrict__ cursor,
    u32*   __restrict__ bucket)
{
  __shared__ float sOut[256 * NCLS];   // 17 KB staging for coalesced poss_edge store
  int tid = threadIdx.x;
  int e = blockIdx.x * 256 + tid;
  int2 ed = ((const int2*)edges)[e];
  int src = ed.x, dst = ed.y;

  // CSR-lite bucket insert: issue early so the atomic overlaps all the math below.
  u32 slot = atomicAdd(cursor + src, 1u);
  if (slot < BCAP) bucket[(size_t)src * BCAP + slot] = (u32)e;

  const uint4* rs4 = (const uint4*)(nodetab + (size_t)src * ROWU);
  const uint4* rd4 = (const uint4*)(nodetab + (size_t)dst * ROWU);

  // logits = h_s + h_d + b - 2*(s.*d)@W2   (h line: u32[16..24])
  uint4 sh0 = rs4[4], dh0 = rd4[4];
  uint4 sh1 = rs4[5], dh1 = rd4[5];
  u32   sh2 = ((const u32*)rs4)[24], dh2 = ((const u32*)rd4)[24];

  float lgt[NCLS];
  {
    u32 sp[9] = {sh0.x, sh0.y, sh0.z, sh0.w, sh1.x, sh1.y, sh1.z, sh1.w, sh2};
    u32 dp[9] = {dh0.x, dh0.y, dh0.z, dh0.w, dh1.x, dh1.y, dh1.z, dh1.w, dh2};
    #pragma unroll
    for (int i = 0; i < 8; ++i) {
      lgt[2 * i]     = lo16(sp[i]) + lo16(dp[i]) + b_trans[2 * i];
      lgt[2 * i + 1] = hi16(sp[i]) + hi16(dp[i]) + b_trans[2 * i + 1];
    }
    lgt[16] = lo16(sp[8]) + lo16(dp[8]) + b_trans[16];
  }

  // cross term, one 8-element k-slice at a time to cap live regs
  #pragma unroll
  for (int q = 0; q < 4; ++q) {
    uint4 sa = rs4[q], da = rd4[q];
    u32 su[4] = {sa.x, sa.y, sa.z, sa.w};
    u32 du[4] = {da.x, da.y, da.z, da.w};
    float p[8];
    #pragma unroll
    for (int j = 0; j < 4; ++j) {
      p[2 * j]     = -2.f * lo16(su[j]) * lo16(du[j]);
      p[2 * j + 1] = -2.f * hi16(su[j]) * hi16(du[j]);
    }
    #pragma unroll
    for (int j = 0; j < 8; ++j) {
      const float* w = W_trans + (EDIM + q * 8 + j) * NCLS;   // uniform -> s_load
      #pragma unroll
      for (int c = 0; c < NCLS; ++c) lgt[c] = fmaf(p[j], w[c], lgt[c]);
    }
  }

  float m = lgt[0];
  #pragma unroll
  for (int c = 1; c < NCLS; ++c) m = fmaxf(m, lgt[c]);
  float sum = 0.f;
  #pragma unroll
  for (int c = 0; c < NCLS; ++c) { lgt[c] = __expf(lgt[c] - m); sum += lgt[c]; }
  float inv = 1.0f / sum;

  #pragma unroll
  for (int c = 0; c < NCLS; ++c) sOut[tid * NCLS + c] = lgt[c] * inv;
  __syncthreads();

  // coalesced float4 poss_edge store
  float4* outp = (float4*)(poss_edge + (size_t)blockIdx.x * 256 * NCLS);
  const float4* sOut4 = (const float4*)sOut;
  for (int i = tid; i < 256 * NCLS / 4; i += 256)
    outp[i] = sOut4[i];
}

// ---------------- Kernel R: gather segment-sum + fused divide ----------------
// thread = (node, class): 17 consecutive lanes read one edge's 17-float poss row
// (coalesced 68 B, L3-resident since edge_kernel just wrote it); bucket/weight
// loads are same-address per 17-lane group (HW broadcast). Stores are coalesced:
// address = 17*block_base + tid exactly.
__global__ __launch_bounds__(256, 8) void reduce_kernel(
    const float* __restrict__ poss_edge,
    const float* __restrict__ weights,
    const u32*   __restrict__ cursor,
    const u32*   __restrict__ bucket,
    const float* __restrict__ nsum,
    float* __restrict__ recall,
    float* __restrict__ poss_node)
{
  int tid = threadIdx.x;
  if (tid >= 255) return;                 // 15 nodes x 17 classes
  int n = blockIdx.x * 15 + tid / 17;
  if (n >= NNODES) return;
  int c = tid - (tid / 17) * 17;

  u32 deg = min(cursor[n], (u32)BCAP);
  const u32* bk = bucket + (size_t)n * BCAP;

  float acc = 0.f;
  for (u32 k = 0; k < deg; ++k) {
    u32 eid = bk[k];                                      // broadcast within group
    acc = fmaf(poss_edge[(size_t)eid * NCLS + c], weights[eid], acc);
  }

  size_t o = (size_t)n * NCLS + c;
  recall[o]    = acc;
  poss_node[o] = acc / nsum[n];
}

// ---------------- Fallback path (old): atomic scatter + separate divide ----------------
__global__ __launch_bounds__(256, 4) void edge_kernel(
    const int*   __restrict__ edges,
    const float* __restrict__ weights,
    const float* __restrict__ W_trans,
    const float* __restrict__ b_trans,
    const u32*   __restrict__ nodetab,
    float* __restrict__ poss_edge,
    float* __restrict__ recall)
{
  __shared__ float sOut[256 * NCLS];
  __shared__ int   sSrc[256];
  int tid = threadIdx.x;
  int e = blockIdx.x * 256 + tid;
  int2 ed = ((const int2*)edges)[e];
  int src = ed.x, dst = ed.y;
  const uint4* rs4 = (const uint4*)(nodetab + (size_t)src * ROWU);
  const uint4* rd4 = (const uint4*)(nodetab + (size_t)dst * ROWU);

  uint4 sh0 = rs4[4], dh0 = rd4[4];
  uint4 sh1 = rs4[5], dh1 = rd4[5];
  u32   sh2 = ((const u32*)rs4)[24], dh2 = ((const u32*)rd4)[24];

  float lgt[NCLS];
  {
    u32 sp[9] = {sh0.x, sh0.y, sh0.z, sh0.w, sh1.x, sh1.y, sh1.z, sh1.w, sh2};
    u32 dp[9] = {dh0.x, dh0.y, dh0.z, dh0.w, dh1.x, dh1.y, dh1.z, dh1.w, dh2};
    #pragma unroll
    for (int i = 0; i < 8; ++i) {
      lgt[2 * i]     = lo16(sp[i]) + lo16(dp[i]) + b_trans[2 * i];
      lgt[2 * i + 1] = hi16(sp[i]) + hi16(dp[i]) + b_trans[2 * i + 1];
    }
    lgt[16] = lo16(sp[8]) + lo16(dp[8]) + b_trans[16];
  }

  #pragma unroll
  for (int q = 0; q < 4; ++q) {
    uint4 sa = rs4[q], da = rd4[q];
    u32 su[4] = {sa.x, sa.y, sa.z, sa.w};
    u32 du[4] = {da.x, da.y, da.z, da.w};
    float p[8];
    #pragma unroll
    for (int j = 0; j < 4; ++j) {
      p[2 * j]     = -2.f * lo16(su[j]) * lo16(du[j]);
      p[2 * j + 1] = -2.f * hi16(su[j]) * hi16(du[j]);
    }
    #pragma unroll
    for (int j = 0; j < 8; ++j) {
      const float* w = W_trans + (EDIM + q * 8 + j) * NCLS;
      #pragma unroll
      for (int c = 0; c < NCLS; ++c) lgt[c] = fmaf(p[j], w[c], lgt[c]);
    }
  }

  float m = lgt[0];
  #pragma unroll
  for (int c = 1; c < NCLS; ++c) m = fmaxf(m, lgt[c]);
  float sum = 0.f;
  #pragma unroll
  for (int c = 0; c < NCLS; ++c) { lgt[c] = __expf(lgt[c] - m); sum += lgt[c]; }
  float inv = 1.0f / sum;
  float wi  = weights[e] * inv;

  sSrc[tid] = src;
  #pragma unroll
  for (int c = 0; c < NCLS; ++c) sOut[tid * NCLS + c] = lgt[c] * inv;
  __syncthreads();

  float4* outp = (float4*)(poss_edge + (size_t)blockIdx.x * 256 * NCLS);
  const float4* sOut4 = (const float4*)sOut;
  for (int i = tid; i < 256 * NCLS / 4; i += 256)
    outp[i] = sOut4[i];
  __syncthreads();

  #pragma unroll
  for (int c = 0; c < NCLS; ++c) sOut[tid * NCLS + c] = lgt[c] * wi;
  __syncthreads();

  for (int i = tid; i < 256 * NCLS; i += 256) {
    unsigned e2 = (unsigned)i / NCLS;
    unsigned c2 = (unsigned)i - e2 * NCLS;
    atomicAdd(recall + (size_t)sSrc[e2] * NCLS + c2, sOut[i]);
  }
}

__global__ __launch_bounds__(256) void div_kernel(
    const float* __restrict__ recall,
    const float* __restrict__ nsum,
    float* __restrict__ poss_node)
{
  int i = blockIdx.x * 256 + threadIdx.x;
  if (i < NNODES * NCLS)
    poss_node[i] = recall[i] / nsum[i / NCLS];
}

extern "C" void kernel_launch(void* const* d_in, const int* in_sizes, int n_in,
                              void* d_out, int out_size, void* d_ws, size_t ws_size,
                              hipStream_t stream) {
  const float* features = (const float*)d_in[0];
  const int*   edges    = (const int*)d_in[1];
  const float* weights  = (const float*)d_in[2];
  const float* nsum     = (const float*)d_in[3];
  const float* W_embed  = (const float*)d_in[4];
  const float* b_embed  = (const float*)d_in[5];
  const float* W_trans  = (const float*)d_in[6];
  const float* b_trans  = (const float*)d_in[7];

  float* out       = (float*)d_out;
  float* poss_node = out;
  float* poss_edge = out + (size_t)NNODES * NCLS;
  float* recall    = out + (size_t)(NNODES + NEDGES) * NCLS;

  u32* nodetab = (u32*)d_ws;                                // 12.8 MB
  size_t need = (size_t)NNODES * ROWU * 4                   // nodetab
              + (size_t)NNODES * 4                          // cursor
              + (size_t)NNODES * BCAP * 4;                  // bucket  -> 38.8 MB total

  if (ws_size >= need) {
    u32* cursor = nodetab + (size_t)NNODES * ROWU;
    u32* bucket = cursor + NNODES;
    hipMemsetAsync(cursor, 0, (size_t)NNODES * sizeof(u32), stream);   // 400 KB
    node_kernel<<<(NNODES + 255) / 256, 256, 0, stream>>>(features, W_embed, b_embed,
                                                          W_trans, nodetab);
    edge_kernel_fast<<<NEDGES / 256, 256, 0, stream>>>(edges, W_trans, b_trans,
                                                       nodetab, poss_edge, cursor, bucket);
    reduce_kernel<<<(NNODES + 14) / 15, 256, 0, stream>>>(poss_edge, weights, cursor,
                                                          bucket, nsum, recall, poss_node);
  } else {
    // fallback: previous atomic-scatter path (workspace too small for buckets)
    hipMemsetAsync(recall, 0, (size_t)NNODES * NCLS * sizeof(float), stream);
    node_kernel<<<(NNODES + 255) / 256, 256, 0, stream>>>(features, W_embed, b_embed,
                                                          W_trans, nodetab);
    edge_kernel<<<NEDGES / 256, 256, 0, stream>>>(edges, weights, W_trans, b_trans,
                                                  nodetab, poss_edge, recall);
    div_kernel<<<(NNODES * NCLS + 255) / 256, 256, 0, stream>>>(recall, nsum, poss_node);
  }
}

// Round 2
// 480.357 us; speedup vs baseline: 1.0307x; 1.0307x over previous
//
#include <hip/hip_runtime.h>

#define NNODES 100000
#define NEDGES 1600000
#define FDIM 128
#define EDIM 32
#define NCLS 17
#define ROWU 32   // per-node row = 32 u32 = 128 B = 2 cachelines:
                  // u32[0..15]  : embed as 32 x bf16 (packed pairs)
                  // u32[16..24] : h = 0.5*lin + sq as 17 x bf16 (packed pairs)
#define BCAP 64   // bucket capacity per node; deg ~ Poisson(16), P(deg>=64) ~ 1e-18

typedef unsigned int u32;

__device__ inline u32 bf16r(float x) {            // round-to-nearest-even bf16
  u32 u = __float_as_uint(x);
  return (u + 0x7FFFu + ((u >> 16) & 1u)) >> 16;
}
__device__ inline u32 pk(float lo, float hi) { return bf16r(lo) | (bf16r(hi) << 16); }
__device__ inline float lo16(u32 u) { return __uint_as_float(u << 16); }
__device__ inline float hi16(u32 u) { return __uint_as_float(u & 0xFFFF0000u); }

// ---------------- Kernel A: per-node embed + h, thread = node, no LDS ----------------
__global__ __launch_bounds__(256) void node_kernel(
    const float* __restrict__ features,
    const float* __restrict__ W_embed,   // [128][32]
    const float* __restrict__ b_embed,   // [32]
    const float* __restrict__ W_trans,   // [64][17]
    u32* __restrict__ nodetab)
{
  int n = blockIdx.x * 256 + threadIdx.x;
  if (n >= NNODES) return;

  float acc[EDIM];
  #pragma unroll
  for (int c = 0; c < EDIM; ++c) acc[c] = b_embed[c];

  const float4* f4 = (const float4*)(features + (size_t)n * FDIM);
  for (int k4 = 0; k4 < FDIM / 4; ++k4) {
    float4 f = f4[k4];
    const float* w = W_embed + k4 * 4 * EDIM;   // uniform -> s_load
    #pragma unroll
    for (int c = 0; c < EDIM; ++c) {
      acc[c] = fmaf(f.x, w[c],            acc[c]);
      acc[c] = fmaf(f.y, w[EDIM + c],     acc[c]);
      acc[c] = fmaf(f.z, w[2 * EDIM + c], acc[c]);
      acc[c] = fmaf(f.w, w[3 * EDIM + c], acc[c]);
    }
  }

  float sq[EDIM];
  #pragma unroll
  for (int k = 0; k < EDIM; ++k) sq[k] = acc[k] * acc[k];

  float h[NCLS + 1];
  #pragma unroll
  for (int c = 0; c < NCLS; ++c) {
    float lin = 0.f, sqs = 0.f;
    #pragma unroll
    for (int k = 0; k < EDIM; ++k) {
      lin = fmaf(acc[k], W_trans[k * NCLS + c],          lin);
      sqs = fmaf(sq[k],  W_trans[(EDIM + k) * NCLS + c], sqs);
    }
    h[c] = 0.5f * lin + sqs;
  }
  h[NCLS] = 0.f;

  u32* row = nodetab + (size_t)n * ROWU;
  u32 p[16];
  #pragma unroll
  for (int i = 0; i < 16; ++i) p[i] = pk(acc[2 * i], acc[2 * i + 1]);
  #pragma unroll
  for (int i = 0; i < 4; ++i)
    ((uint4*)row)[i] = make_uint4(p[4 * i], p[4 * i + 1], p[4 * i + 2], p[4 * i + 3]);
  #pragma unroll
  for (int i = 0; i < 9; ++i) row[16 + i] = pk(h[2 * i], h[2 * i + 1]);
}

// ---------------- Kernel B: per-edge softmax; scatter bucket id (+weight) ----------------
// HASW=1: bucket entry = uint2(eid, weight_bits)  (removes random weights gather
// from the reduce). HASW=0: entry = u32 eid (smaller workspace).
template <int HASW>
__global__ __launch_bounds__(256, 4) void edge_kernel_fast_t(
    const int*   __restrict__ edges,
    const float* __restrict__ weights,
    const float* __restrict__ W_trans,
    const float* __restrict__ b_trans,
    const u32*   __restrict__ nodetab,
    float* __restrict__ poss_edge,
    u32*   __restrict__ cursor,
    u32*   __restrict__ bucket)
{
  __shared__ float sOut[256 * NCLS];   // 17 KB staging for coalesced poss_edge store
  int tid = threadIdx.x;
  int e = blockIdx.x * 256 + tid;
  int2 ed = ((const int2*)edges)[e];
  int src = ed.x, dst = ed.y;

  // CSR-lite bucket insert: issue early so the atomic overlaps all the math below.
  u32 slot = atomicAdd(cursor + src, 1u);
  if (slot < BCAP) {
    if (HASW)
      ((uint2*)bucket)[(size_t)src * BCAP + slot] =
          make_uint2((u32)e, __float_as_uint(weights[e]));
    else
      bucket[(size_t)src * BCAP + slot] = (u32)e;
  }

  const uint4* rs4 = (const uint4*)(nodetab + (size_t)src * ROWU);
  const uint4* rd4 = (const uint4*)(nodetab + (size_t)dst * ROWU);

  // logits = h_s + h_d + b - 2*(s.*d)@W2   (h line: u32[16..24])
  uint4 sh0 = rs4[4], dh0 = rd4[4];
  uint4 sh1 = rs4[5], dh1 = rd4[5];
  u32   sh2 = ((const u32*)rs4)[24], dh2 = ((const u32*)rd4)[24];

  float lgt[NCLS];
  {
    u32 sp[9] = {sh0.x, sh0.y, sh0.z, sh0.w, sh1.x, sh1.y, sh1.z, sh1.w, sh2};
    u32 dp[9] = {dh0.x, dh0.y, dh0.z, dh0.w, dh1.x, dh1.y, dh1.z, dh1.w, dh2};
    #pragma unroll
    for (int i = 0; i < 8; ++i) {
      lgt[2 * i]     = lo16(sp[i]) + lo16(dp[i]) + b_trans[2 * i];
      lgt[2 * i + 1] = hi16(sp[i]) + hi16(dp[i]) + b_trans[2 * i + 1];
    }
    lgt[16] = lo16(sp[8]) + lo16(dp[8]) + b_trans[16];
  }

  // cross term, one 8-element k-slice at a time to cap live regs
  #pragma unroll
  for (int q = 0; q < 4; ++q) {
    uint4 sa = rs4[q], da = rd4[q];
    u32 su[4] = {sa.x, sa.y, sa.z, sa.w};
    u32 du[4] = {da.x, da.y, da.z, da.w};
    float p[8];
    #pragma unroll
    for (int j = 0; j < 4; ++j) {
      p[2 * j]     = -2.f * lo16(su[j]) * lo16(du[j]);
      p[2 * j + 1] = -2.f * hi16(su[j]) * hi16(du[j]);
    }
    #pragma unroll
    for (int j = 0; j < 8; ++j) {
      const float* w = W_trans + (EDIM + q * 8 + j) * NCLS;   // uniform -> s_load
      #pragma unroll
      for (int c = 0; c < NCLS; ++c) lgt[c] = fmaf(p[j], w[c], lgt[c]);
    }
  }

  float m = lgt[0];
  #pragma unroll
  for (int c = 1; c < NCLS; ++c) m = fmaxf(m, lgt[c]);
  float sum = 0.f;
  #pragma unroll
  for (int c = 0; c < NCLS; ++c) { lgt[c] = __expf(lgt[c] - m); sum += lgt[c]; }
  float inv = 1.0f / sum;

  #pragma unroll
  for (int c = 0; c < NCLS; ++c) sOut[tid * NCLS + c] = lgt[c] * inv;
  __syncthreads();

  // coalesced float4 poss_edge store
  float4* outp = (float4*)(poss_edge + (size_t)blockIdx.x * 256 * NCLS);
  const float4* sOut4 = (const float4*)sOut;
  for (int i = tid; i < 256 * NCLS / 4; i += 256)
    outp[i] = sOut4[i];
}

// ---------------- Kernel R: gather segment-sum + fused divide, 4-deep MLP ----------------
// thread = (node, class): 17 consecutive lanes read one edge's 17-float poss row
// (coalesced 68 B, L3-resident); bucket loads merge to dwordx4 (rows 512 B aligned).
// 4 edges in flight per thread x 8 waves/SIMD hides the L3 gather latency.
template <int HASW>
__global__ __launch_bounds__(256, 8) void reduce_kernel_t(
    const float* __restrict__ poss_edge,
    const float* __restrict__ weights,    // only read when !HASW
    const u32*   __restrict__ cursor,
    const u32*   __restrict__ bucket,
    const float* __restrict__ nsum,
    float* __restrict__ recall,
    float* __restrict__ poss_node)
{
  int tid = threadIdx.x;
  if (tid >= 255) return;                 // 15 nodes x 17 classes
  int g = tid / 17;
  int n = blockIdx.x * 15 + g;
  if (n >= NNODES) return;
  int c = tid - g * 17;

  u32 deg = min(cursor[n], (u32)BCAP);
  float ns = nsum[n];

  float acc = 0.f;
  u32 k = 0;
  if (HASW) {
    const uint2* bk = (const uint2*)bucket + (size_t)n * BCAP;
    for (; k + 4 <= deg; k += 4) {
      uint2 b0 = bk[k], b1 = bk[k + 1], b2 = bk[k + 2], b3 = bk[k + 3];
      float p0 = poss_edge[(size_t)b0.x * NCLS + c];
      float p1 = poss_edge[(size_t)b1.x * NCLS + c];
      float p2 = poss_edge[(size_t)b2.x * NCLS + c];
      float p3 = poss_edge[(size_t)b3.x * NCLS + c];
      acc = fmaf(p0, __uint_as_float(b0.y), acc);
      acc = fmaf(p1, __uint_as_float(b1.y), acc);
      acc = fmaf(p2, __uint_as_float(b2.y), acc);
      acc = fmaf(p3, __uint_as_float(b3.y), acc);
    }
    for (; k < deg; ++k) {
      uint2 b = bk[k];
      acc = fmaf(poss_edge[(size_t)b.x * NCLS + c], __uint_as_float(b.y), acc);
    }
  } else {
    const u32* bk = bucket + (size_t)n * BCAP;
    for (; k + 4 <= deg; k += 4) {
      u32 e0 = bk[k], e1 = bk[k + 1], e2 = bk[k + 2], e3 = bk[k + 3];
      float p0 = poss_edge[(size_t)e0 * NCLS + c];
      float p1 = poss_edge[(size_t)e1 * NCLS + c];
      float p2 = poss_edge[(size_t)e2 * NCLS + c];
      float p3 = poss_edge[(size_t)e3 * NCLS + c];
      float w0 = weights[e0], w1 = weights[e1], w2 = weights[e2], w3 = weights[e3];
      acc = fmaf(p0, w0, acc);
      acc = fmaf(p1, w1, acc);
      acc = fmaf(p2, w2, acc);
      acc = fmaf(p3, w3, acc);
    }
    for (; k < deg; ++k) {
      u32 e0 = bk[k];
      acc = fmaf(poss_edge[(size_t)e0 * NCLS + c], weights[e0], acc);
    }
  }

  size_t o = (size_t)n * NCLS + c;
  recall[o]    = acc;
  poss_node[o] = acc / ns;
}

// ---------------- Fallback path (old): atomic scatter + separate divide ----------------
__global__ __launch_bounds__(256, 4) void edge_kernel(
    const int*   __restrict__ edges,
    const float* __restrict__ weights,
    const float* __restrict__ W_trans,
    const float* __restrict__ b_trans,
    const u32*   __restrict__ nodetab,
    float* __restrict__ poss_edge,
    float* __restrict__ recall)
{
  __shared__ float sOut[256 * NCLS];
  __shared__ int   sSrc[256];
  int tid = threadIdx.x;
  int e = blockIdx.x * 256 + tid;
  int2 ed = ((const int2*)edges)[e];
  int src = ed.x, dst = ed.y;
  const uint4* rs4 = (const uint4*)(nodetab + (size_t)src * ROWU);
  const uint4* rd4 = (const uint4*)(nodetab + (size_t)dst * ROWU);

  uint4 sh0 = rs4[4], dh0 = rd4[4];
  uint4 sh1 = rs4[5], dh1 = rd4[5];
  u32   sh2 = ((const u32*)rs4)[24], dh2 = ((const u32*)rd4)[24];

  float lgt[NCLS];
  {
    u32 sp[9] = {sh0.x, sh0.y, sh0.z, sh0.w, sh1.x, sh1.y, sh1.z, sh1.w, sh2};
    u32 dp[9] = {dh0.x, dh0.y, dh0.z, dh0.w, dh1.x, dh1.y, dh1.z, dh1.w, dh2};
    #pragma unroll
    for (int i = 0; i < 8; ++i) {
      lgt[2 * i]     = lo16(sp[i]) + lo16(dp[i]) + b_trans[2 * i];
      lgt[2 * i + 1] = hi16(sp[i]) + hi16(dp[i]) + b_trans[2 * i + 1];
    }
    lgt[16] = lo16(sp[8]) + lo16(dp[8]) + b_trans[16];
  }

  #pragma unroll
  for (int q = 0; q < 4; ++q) {
    uint4 sa = rs4[q], da = rd4[q];
    u32 su[4] = {sa.x, sa.y, sa.z, sa.w};
    u32 du[4] = {da.x, da.y, da.z, da.w};
    float p[8];
    #pragma unroll
    for (int j = 0; j < 4; ++j) {
      p[2 * j]     = -2.f * lo16(su[j]) * lo16(du[j]);
      p[2 * j + 1] = -2.f * hi16(su[j]) * hi16(du[j]);
    }
    #pragma unroll
    for (int j = 0; j < 8; ++j) {
      const float* w = W_trans + (EDIM + q * 8 + j) * NCLS;
      #pragma unroll
      for (int c = 0; c < NCLS; ++c) lgt[c] = fmaf(p[j], w[c], lgt[c]);
    }
  }

  float m = lgt[0];
  #pragma unroll
  for (int c = 1; c < NCLS; ++c) m = fmaxf(m, lgt[c]);
  float sum = 0.f;
  #pragma unroll
  for (int c = 0; c < NCLS; ++c) { lgt[c] = __expf(lgt[c] - m); sum += lgt[c]; }
  float inv = 1.0f / sum;
  float wi  = weights[e] * inv;

  sSrc[tid] = src;
  #pragma unroll
  for (int c = 0; c < NCLS; ++c) sOut[tid * NCLS + c] = lgt[c] * inv;
  __syncthreads();

  float4* outp = (float4*)(poss_edge + (size_t)blockIdx.x * 256 * NCLS);
  const float4* sOut4 = (const float4*)sOut;
  for (int i = tid; i < 256 * NCLS / 4; i += 256)
    outp[i] = sOut4[i];
  __syncthreads();

  #pragma unroll
  for (int c = 0; c < NCLS; ++c) sOut[tid * NCLS + c] = lgt[c] * wi;
  __syncthreads();

  for (int i = tid; i < 256 * NCLS; i += 256) {
    unsigned e2 = (unsigned)i / NCLS;
    unsigned c2 = (unsigned)i - e2 * NCLS;
    atomicAdd(recall + (size_t)sSrc[e2] * NCLS + c2, sOut[i]);
  }
}

__global__ __launch_bounds__(256) void div_kernel(
    const float* __restrict__ recall,
    const float* __restrict__ nsum,
    float* __restrict__ poss_node)
{
  int i = blockIdx.x * 256 + threadIdx.x;
  if (i < NNODES * NCLS)
    poss_node[i] = recall[i] / nsum[i / NCLS];
}

extern "C" void kernel_launch(void* const* d_in, const int* in_sizes, int n_in,
                              void* d_out, int out_size, void* d_ws, size_t ws_size,
                              hipStream_t stream) {
  const float* features = (const float*)d_in[0];
  const int*   edges    = (const int*)d_in[1];
  const float* weights  = (const float*)d_in[2];
  const float* nsum     = (const float*)d_in[3];
  const float* W_embed  = (const float*)d_in[4];
  const float* b_embed  = (const float*)d_in[5];
  const float* W_trans  = (const float*)d_in[6];
  const float* b_trans  = (const float*)d_in[7];

  float* out       = (float*)d_out;
  float* poss_node = out;
  float* poss_edge = out + (size_t)NNODES * NCLS;
  float* recall    = out + (size_t)(NNODES + NEDGES) * NCLS;

  u32* nodetab = (u32*)d_ws;                                 // 12.8 MB
  size_t base   = (size_t)NNODES * ROWU * 4 + (size_t)NNODES * 4;  // nodetab + cursor
  size_t need_w = base + (size_t)NNODES * BCAP * 8;          // uint2 bucket -> 64.4 MB
  size_t need_e = base + (size_t)NNODES * BCAP * 4;          // u32 bucket   -> 38.8 MB
  u32* cursor = nodetab + (size_t)NNODES * ROWU;
  u32* bucket = cursor + NNODES;

  if (ws_size >= need_w) {
    hipMemsetAsync(cursor, 0, (size_t)NNODES * sizeof(u32), stream);
    node_kernel<<<(NNODES + 255) / 256, 256, 0, stream>>>(features, W_embed, b_embed,
                                                          W_trans, nodetab);
    edge_kernel_fast_t<1><<<NEDGES / 256, 256, 0, stream>>>(edges, weights, W_trans,
                                                            b_trans, nodetab, poss_edge,
                                                            cursor, bucket);
    reduce_kernel_t<1><<<(NNODES + 14) / 15, 256, 0, stream>>>(poss_edge, weights, cursor,
                                                               bucket, nsum, recall,
                                                               poss_node);
  } else if (ws_size >= need_e) {
    hipMemsetAsync(cursor, 0, (size_t)NNODES * sizeof(u32), stream);
    node_kernel<<<(NNODES + 255) / 256, 256, 0, stream>>>(features, W_embed, b_embed,
                                                          W_trans, nodetab);
    edge_kernel_fast_t<0><<<NEDGES / 256, 256, 0, stream>>>(edges, weights, W_trans,
                                                            b_trans, nodetab, poss_edge,
                                                            cursor, bucket);
    reduce_kernel_t<0><<<(NNODES + 14) / 15, 256, 0, stream>>>(poss_edge, weights, cursor,
                                                               bucket, nsum, recall,
                                                               poss_node);
  } else {
    // fallback: atomic-scatter path (workspace too small for buckets)
    hipMemsetAsync(recall, 0, (size_t)NNODES * NCLS * sizeof(float), stream);
    node_kernel<<<(NNODES + 255) / 256, 256, 0, stream>>>(features, W_embed, b_embed,
                                                          W_trans, nodetab);
    edge_kernel<<<NEDGES / 256, 256, 0, stream>>>(edges, weights, W_trans, b_trans,
                                                  nodetab, poss_edge, recall);
    div_kernel<<<(NNODES * NCLS + 255) / 256, 256, 0, stream>>>(recall, nsum, poss_node);
  }
}

// Round 3
// 383.744 us; speedup vs baseline: 1.2902x; 1.2518x over previous
//
#include <hip/hip_runtime.h>

#define NNODES 100000
#define NEDGES 1600000
#define FDIM 128
#define EDIM 32
#define NCLS 17
#define ROWU 16   // embed-only row: 16 u32 = 32 x bf16 = 64 B = ONE cache line
#define BCAP 64   // bucket capacity per node; deg ~ Poisson(16), P(deg>=64) ~ 1e-18

typedef unsigned int u32;

__device__ inline u32 bf16r(float x) {            // round-to-nearest-even bf16
  u32 u = __float_as_uint(x);
  return (u + 0x7FFFu + ((u >> 16) & 1u)) >> 16;
}
__device__ inline u32 pk(float lo, float hi) { return bf16r(lo) | (bf16r(hi) << 16); }
__device__ inline float lo16(u32 u) { return __uint_as_float(u << 16); }
__device__ inline float hi16(u32 u) { return __uint_as_float(u & 0xFFFF0000u); }

// ---------------- Kernel A: per-node embed only, 64-thread blocks ----------------
// 1563 blocks spread over 256 CUs (vs 391 before: load imbalance). No h-pass.
__global__ __launch_bounds__(64) void node_kernel(
    const float* __restrict__ features,
    const float* __restrict__ W_embed,   // [128][32]
    const float* __restrict__ b_embed,   // [32]
    u32* __restrict__ nodetab)
{
  int n = blockIdx.x * 64 + threadIdx.x;
  if (n >= NNODES) return;

  float acc[EDIM];
  #pragma unroll
  for (int c = 0; c < EDIM; ++c) acc[c] = b_embed[c];

  const float4* f4 = (const float4*)(features + (size_t)n * FDIM);
  for (int k4 = 0; k4 < FDIM / 4; ++k4) {
    float4 f = f4[k4];
    const float* w = W_embed + k4 * 4 * EDIM;   // uniform -> s_load
    #pragma unroll
    for (int c = 0; c < EDIM; ++c) {
      acc[c] = fmaf(f.x, w[c],            acc[c]);
      acc[c] = fmaf(f.y, w[EDIM + c],     acc[c]);
      acc[c] = fmaf(f.z, w[2 * EDIM + c], acc[c]);
      acc[c] = fmaf(f.w, w[3 * EDIM + c], acc[c]);
    }
  }

  u32 p[16];
  #pragma unroll
  for (int i = 0; i < 16; ++i) p[i] = pk(acc[2 * i], acc[2 * i + 1]);
  uint4* row = (uint4*)(nodetab + (size_t)n * ROWU);
  #pragma unroll
  for (int i = 0; i < 4; ++i)
    row[i] = make_uint4(p[4 * i], p[4 * i + 1], p[4 * i + 2], p[4 * i + 3]);
}

// ---------------- Kernel B: per-edge logits from embeds directly ----------------
// logits[c] = b[c] + sum_k 0.5*(s+d)_k * W1[k][c] + ((s-d)_k)^2 * W2[k][c]
// Row gather = 8 hoisted uint4 loads touching 2 lines/edge (was 14 loads / 4 lines).
// FAST=1: scatter uint2(eid, w) bucket entry. FAST=0: old fp32 atomic scatter tail.
template <int FAST>
__global__ __launch_bounds__(256, 4) void edge_kernel3(
    const int*   __restrict__ edges,
    const float* __restrict__ weights,
    const float* __restrict__ W_trans,   // [64][17]
    const float* __restrict__ b_trans,   // [17]
    const u32*   __restrict__ nodetab,
    float* __restrict__ poss_edge,
    u32*   __restrict__ cursor,          // FAST
    u32*   __restrict__ bucket,          // FAST (uint2 entries)
    float* __restrict__ recall)          // !FAST
{
  __shared__ float sOut[256 * NCLS];   // 17 KB staging for coalesced poss_edge store
  __shared__ int   sSrc[256];          // fallback tail only
  int tid = threadIdx.x;
  int e = blockIdx.x * 256 + tid;
  int2 ed = ((const int2*)edges)[e];
  int src = ed.x, dst = ed.y;

  const uint4* rs4 = (const uint4*)(nodetab + (size_t)src * ROWU);
  const uint4* rd4 = (const uint4*)(nodetab + (size_t)dst * ROWU);
  // hoist ALL row loads: one gather-latency round per edge
  uint4 sq[4] = {rs4[0], rs4[1], rs4[2], rs4[3]};
  uint4 dq[4] = {rd4[0], rd4[1], rd4[2], rd4[3]};
  float w = weights[e];

  if (FAST) {
    // CSR-lite bucket insert, issued early to overlap the math below
    u32 slot = atomicAdd(cursor + src, 1u);
    if (slot < BCAP)
      ((uint2*)bucket)[(size_t)src * BCAP + slot] =
          make_uint2((u32)e, __float_as_uint(w));
  }

  float lgt[NCLS];
  #pragma unroll
  for (int c = 0; c < NCLS; ++c) lgt[c] = b_trans[c];

  #pragma unroll
  for (int q = 0; q < 4; ++q) {
    u32 su[4] = {sq[q].x, sq[q].y, sq[q].z, sq[q].w};
    u32 du[4] = {dq[q].x, dq[q].y, dq[q].z, dq[q].w};
    float uu[8], vv[8];
    #pragma unroll
    for (int j = 0; j < 4; ++j) {
      float sl = lo16(su[j]), sh = hi16(su[j]);
      float dl = lo16(du[j]), dh = hi16(du[j]);
      uu[2 * j]     = 0.5f * (sl + dl);
      uu[2 * j + 1] = 0.5f * (sh + dh);
      float t0 = sl - dl, t1 = sh - dh;
      vv[2 * j]     = t0 * t0;
      vv[2 * j + 1] = t1 * t1;
    }
    #pragma unroll
    for (int t = 0; t < 8; ++t) {
      const float* w1 = W_trans + (q * 8 + t) * NCLS;          // uniform -> s_load
      const float* w2 = W_trans + (EDIM + q * 8 + t) * NCLS;   // uniform -> s_load
      #pragma unroll
      for (int c = 0; c < NCLS; ++c) {
        lgt[c] = fmaf(uu[t], w1[c], lgt[c]);
        lgt[c] = fmaf(vv[t], w2[c], lgt[c]);
      }
    }
  }

  float m = lgt[0];
  #pragma unroll
  for (int c = 1; c < NCLS; ++c) m = fmaxf(m, lgt[c]);
  float sum = 0.f;
  #pragma unroll
  for (int c = 0; c < NCLS; ++c) { lgt[c] = __expf(lgt[c] - m); sum += lgt[c]; }
  float inv = 1.0f / sum;

  #pragma unroll
  for (int c = 0; c < NCLS; ++c) sOut[tid * NCLS + c] = lgt[c] * inv;
  __syncthreads();

  // coalesced float4 poss_edge store
  float4* outp = (float4*)(poss_edge + (size_t)blockIdx.x * 256 * NCLS);
  const float4* sOut4 = (const float4*)sOut;
  for (int i = tid; i < 256 * NCLS / 4; i += 256)
    outp[i] = sOut4[i];

  if (!FAST) {
    __syncthreads();
    float wi = w * inv;
    sSrc[tid] = src;
    #pragma unroll
    for (int c = 0; c < NCLS; ++c) sOut[tid * NCLS + c] = lgt[c] * wi;
    __syncthreads();
    for (int i = tid; i < 256 * NCLS; i += 256) {
      unsigned e2 = (unsigned)i / NCLS;
      unsigned c2 = (unsigned)i - e2 * NCLS;
      atomicAdd(recall + (size_t)sSrc[e2] * NCLS + c2, sOut[i]);
    }
  }
}

// ---------------- Kernel R: gather segment-sum + fused divide, 4-deep MLP ----------------
__global__ __launch_bounds__(256, 8) void reduce_kernel(
    const float* __restrict__ poss_edge,
    const u32*   __restrict__ cursor,
    const u32*   __restrict__ bucket,    // uint2 entries (eid, weight_bits)
    const float* __restrict__ nsum,
    float* __restrict__ recall,
    float* __restrict__ poss_node)
{
  int tid = threadIdx.x;
  if (tid >= 255) return;                 // 15 nodes x 17 classes
  int g = tid / 17;
  int n = blockIdx.x * 15 + g;
  if (n >= NNODES) return;
  int c = tid - g * 17;

  u32 deg = min(cursor[n], (u32)BCAP);
  float ns = nsum[n];
  const uint2* bk = (const uint2*)bucket + (size_t)n * BCAP;

  float acc = 0.f;
  u32 k = 0;
  for (; k + 4 <= deg; k += 4) {
    uint2 b0 = bk[k], b1 = bk[k + 1], b2 = bk[k + 2], b3 = bk[k + 3];
    float p0 = poss_edge[(size_t)b0.x * NCLS + c];
    float p1 = poss_edge[(size_t)b1.x * NCLS + c];
    float p2 = poss_edge[(size_t)b2.x * NCLS + c];
    float p3 = poss_edge[(size_t)b3.x * NCLS + c];
    acc = fmaf(p0, __uint_as_float(b0.y), acc);
    acc = fmaf(p1, __uint_as_float(b1.y), acc);
    acc = fmaf(p2, __uint_as_float(b2.y), acc);
    acc = fmaf(p3, __uint_as_float(b3.y), acc);
  }
  for (; k < deg; ++k) {
    uint2 b = bk[k];
    acc = fmaf(poss_edge[(size_t)b.x * NCLS + c], __uint_as_float(b.y), acc);
  }

  size_t o = (size_t)n * NCLS + c;
  recall[o]    = acc;
  poss_node[o] = acc / ns;
}

// ---------------- Fallback divide ----------------
__global__ __launch_bounds__(256) void div_kernel(
    const float* __restrict__ recall,
    const float* __restrict__ nsum,
    float* __restrict__ poss_node)
{
  int i = blockIdx.x * 256 + threadIdx.x;
  if (i < NNODES * NCLS)
    poss_node[i] = recall[i] / nsum[i / NCLS];
}

extern "C" void kernel_launch(void* const* d_in, const int* in_sizes, int n_in,
                              void* d_out, int out_size, void* d_ws, size_t ws_size,
                              hipStream_t stream) {
  const float* features = (const float*)d_in[0];
  const int*   edges    = (const int*)d_in[1];
  const float* weights  = (const float*)d_in[2];
  const float* nsum     = (const float*)d_in[3];
  const float* W_embed  = (const float*)d_in[4];
  const float* b_embed  = (const float*)d_in[5];
  const float* W_trans  = (const float*)d_in[6];
  const float* b_trans  = (const float*)d_in[7];

  float* out       = (float*)d_out;
  float* poss_node = out;
  float* poss_edge = out + (size_t)NNODES * NCLS;
  float* recall    = out + (size_t)(NNODES + NEDGES) * NCLS;

  u32* nodetab = (u32*)d_ws;                                 // 6.4 MB
  u32* cursor  = nodetab + (size_t)NNODES * ROWU;            // 0.4 MB
  u32* bucket  = cursor + NNODES;                            // 51.2 MB (uint2)
  size_t need = (size_t)NNODES * ROWU * 4 + (size_t)NNODES * 4
              + (size_t)NNODES * BCAP * 8;                   // 58.0 MB total

  if (ws_size >= need) {
    hipMemsetAsync(cursor, 0, (size_t)NNODES * sizeof(u32), stream);
    node_kernel<<<(NNODES + 63) / 64, 64, 0, stream>>>(features, W_embed, b_embed,
                                                       nodetab);
    edge_kernel3<1><<<NEDGES / 256, 256, 0, stream>>>(edges, weights, W_trans, b_trans,
                                                      nodetab, poss_edge, cursor, bucket,
                                                      nullptr);
    reduce_kernel<<<(NNODES + 14) / 15, 256, 0, stream>>>(poss_edge, cursor, bucket,
                                                          nsum, recall, poss_node);
  } else {
    // fallback: fp32 atomic scatter + separate divide (workspace too small)
    hipMemsetAsync(recall, 0, (size_t)NNODES * NCLS * sizeof(float), stream);
    node_kernel<<<(NNODES + 63) / 64, 64, 0, stream>>>(features, W_embed, b_embed,
                                                       nodetab);
    edge_kernel3<0><<<NEDGES / 256, 256, 0, stream>>>(edges, weights, W_trans, b_trans,
                                                      nodetab, poss_edge, nullptr, nullptr,
                                                      recall);
    div_kernel<<<(NNODES * NCLS + 255) / 256, 256, 0, stream>>>(recall, nsum, poss_node);
  }
}

// Round 4
// 372.713 us; speedup vs baseline: 1.3284x; 1.0296x over previous
//
#include <hip/hip_runtime.h>

#define NNODES 100000
#define NEDGES 1600000
#define FDIM 128
#define EDIM 32
#define NCLS 17
#define ROWU 16   // embed-only row: 16 u32 = 32 x f16 = 64 B = ONE cache line
#define BCAP 64   // bucket capacity per node; deg ~ Poisson(16), P(deg>=64) ~ 1e-18
#define WPK (16 * NCLS)   // packed half2 table entries per half (u- and v- tables)

typedef unsigned int u32;
typedef _Float16 h2 __attribute__((ext_vector_type(2)));

__device__ inline h2 bch(u32 x) { return __builtin_bit_cast(h2, x); }

// dot2: acc += a[0]*w[0] + a[1]*w[1], f32 accumulate
__device__ inline float dot2acc(h2 a, u32 wbits, float acc) {
#if __has_builtin(__builtin_amdgcn_fdot2)
  return __builtin_amdgcn_fdot2(a, bch(wbits), acc, false);
#else
  h2 w = bch(wbits);
  acc = fmaf((float)a[0], (float)w[0], acc);
  return fmaf((float)a[1], (float)w[1], acc);
#endif
}

// ---------------- Kernel P: pack W_trans into half2 tables ----------------
// wpack[0      .. WPK-1] : (0.5*W1[2k][c], 0.5*W1[2k+1][c])  for u = (s+d)
// wpack[WPK .. 2*WPK-1]  : (    W2[2k][c],     W2[2k+1][c])  for v = (s-d)^2
__global__ __launch_bounds__(256) void prep_kernel(
    const float* __restrict__ W_trans, u32* __restrict__ wpack)
{
  for (int x = threadIdx.x; x < 2 * WPK; x += 256) {
    int tab = x / WPK;
    int r   = x - tab * WPK;
    int k2  = r / NCLS, c = r - k2 * NCLS;
    int row0 = tab ? (EDIM + 2 * k2) : (2 * k2);
    float a = W_trans[row0 * NCLS + c];
    float b = W_trans[(row0 + 1) * NCLS + c];
    if (!tab) { a *= 0.5f; b *= 0.5f; }
    h2 p; p[0] = (_Float16)a; p[1] = (_Float16)b;
    wpack[x] = __builtin_bit_cast(u32, p);
  }
}

// ---------------- Kernel A: per-node embed only, 64-thread blocks ----------------
__global__ __launch_bounds__(64) void node_kernel(
    const float* __restrict__ features,
    const float* __restrict__ W_embed,   // [128][32]
    const float* __restrict__ b_embed,   // [32]
    u32* __restrict__ nodetab)
{
  int n = blockIdx.x * 64 + threadIdx.x;
  if (n >= NNODES) return;

  float acc[EDIM];
  #pragma unroll
  for (int c = 0; c < EDIM; ++c) acc[c] = b_embed[c];

  const float4* f4 = (const float4*)(features + (size_t)n * FDIM);
  for (int k4 = 0; k4 < FDIM / 4; ++k4) {
    float4 f = f4[k4];
    const float* w = W_embed + k4 * 4 * EDIM;   // uniform -> s_load
    #pragma unroll
    for (int c = 0; c < EDIM; ++c) {
      acc[c] = fmaf(f.x, w[c],            acc[c]);
      acc[c] = fmaf(f.y, w[EDIM + c],     acc[c]);
      acc[c] = fmaf(f.z, w[2 * EDIM + c], acc[c]);
      acc[c] = fmaf(f.w, w[3 * EDIM + c], acc[c]);
    }
  }

  u32 p[16];
  #pragma unroll
  for (int i = 0; i < 16; ++i) {
    h2 t; t[0] = (_Float16)acc[2 * i]; t[1] = (_Float16)acc[2 * i + 1];
    p[i] = __builtin_bit_cast(u32, t);
  }
  uint4* row = (uint4*)(nodetab + (size_t)n * ROWU);
  #pragma unroll
  for (int i = 0; i < 4; ++i)
    row[i] = make_uint4(p[4 * i], p[4 * i + 1], p[4 * i + 2], p[4 * i + 3]);
}

// ---------------- Kernel B: per-edge logits, packed-f16 dot2 ----------------
// logits[c] = b[c] + sum_k2 dot2((s+d)_k2, 0.5*W1_k2[c]) + dot2(((s-d)^2)_k2, W2_k2[c])
// Row gather = 8 hoisted uint4 loads touching 2 lines/edge. u,v stay packed f16.
// FAST=1: scatter uint2(eid, w) bucket entry. FAST=0: fp32 atomic scatter tail.
template <int FAST>
__global__ __launch_bounds__(256, 4) void edge_kernel4(
    const int*   __restrict__ edges,
    const float* __restrict__ weights,
    const u32*   __restrict__ wpack,     // 2*WPK packed half2 (uniform -> s_load)
    const float* __restrict__ b_trans,   // [17]
    const u32*   __restrict__ nodetab,
    float* __restrict__ poss_edge,
    u32*   __restrict__ cursor,          // FAST
    u32*   __restrict__ bucket,          // FAST (uint2 entries)
    float* __restrict__ recall)          // !FAST
{
  __shared__ float sOut[256 * NCLS];   // 17 KB staging for coalesced poss_edge store
  __shared__ int   sSrc[256];          // fallback tail only
  int tid = threadIdx.x;
  int e = blockIdx.x * 256 + tid;
  int2 ed = ((const int2*)edges)[e];
  int src = ed.x, dst = ed.y;

  const uint4* rs4 = (const uint4*)(nodetab + (size_t)src * ROWU);
  const uint4* rd4 = (const uint4*)(nodetab + (size_t)dst * ROWU);
  // hoist ALL row loads: one gather-latency round per edge
  uint4 sq[4] = {rs4[0], rs4[1], rs4[2], rs4[3]};
  uint4 dq[4] = {rd4[0], rd4[1], rd4[2], rd4[3]};
  float w = weights[e];

  if (FAST) {
    // CSR-lite bucket insert, issued early to overlap the math below
    u32 slot = atomicAdd(cursor + src, 1u);
    if (slot < BCAP)
      ((uint2*)bucket)[(size_t)src * BCAP + slot] =
          make_uint2((u32)e, __float_as_uint(w));
  }

  float lgt[NCLS];
  #pragma unroll
  for (int c = 0; c < NCLS; ++c) lgt[c] = b_trans[c];

  #pragma unroll
  for (int q = 0; q < 4; ++q) {
    u32 su[4] = {sq[q].x, sq[q].y, sq[q].z, sq[q].w};
    u32 du[4] = {dq[q].x, dq[q].y, dq[q].z, dq[q].w};
    #pragma unroll
    for (int j = 0; j < 4; ++j) {
      int k2 = q * 4 + j;
      h2 s2 = bch(su[j]), d2 = bch(du[j]);
      h2 uu = s2 + d2;                 // v_pk_add_f16 (0.5 folded into W1 table)
      h2 t  = s2 - d2;
      h2 vv = t * t;                   // v_pk_mul_f16
      const u32* w1 = wpack + k2 * NCLS;         // uniform -> s_load
      const u32* w2 = wpack + WPK + k2 * NCLS;
      #pragma unroll
      for (int c = 0; c < NCLS; ++c) {
        lgt[c] = dot2acc(uu, w1[c], lgt[c]);
        lgt[c] = dot2acc(vv, w2[c], lgt[c]);
      }
    }
  }

  float m = lgt[0];
  #pragma unroll
  for (int c = 1; c < NCLS; ++c) m = fmaxf(m, lgt[c]);
  float sum = 0.f;
  #pragma unroll
  for (int c = 0; c < NCLS; ++c) { lgt[c] = __expf(lgt[c] - m); sum += lgt[c]; }
  float inv = 1.0f / sum;

  #pragma unroll
  for (int c = 0; c < NCLS; ++c) sOut[tid * NCLS + c] = lgt[c] * inv;
  __syncthreads();

  // coalesced float4 poss_edge store
  float4* outp = (float4*)(poss_edge + (size_t)blockIdx.x * 256 * NCLS);
  const float4* sOut4 = (const float4*)sOut;
  for (int i = tid; i < 256 * NCLS / 4; i += 256)
    outp[i] = sOut4[i];

  if (!FAST) {
    __syncthreads();
    float wi = w * inv;
    sSrc[tid] = src;
    #pragma unroll
    for (int c = 0; c < NCLS; ++c) sOut[tid * NCLS + c] = lgt[c] * wi;
    __syncthreads();
    for (int i = tid; i < 256 * NCLS; i += 256) {
      unsigned e2 = (unsigned)i / NCLS;
      unsigned c2 = (unsigned)i - e2 * NCLS;
      atomicAdd(recall + (size_t)sSrc[e2] * NCLS + c2, sOut[i]);
    }
  }
}

// ---------------- Kernel R: gather segment-sum + fused divide, 4-deep MLP ----------------
__global__ __launch_bounds__(256, 8) void reduce_kernel(
    const float* __restrict__ poss_edge,
    const u32*   __restrict__ cursor,
    const u32*   __restrict__ bucket,    // uint2 entries (eid, weight_bits)
    const float* __restrict__ nsum,
    float* __restrict__ recall,
    float* __restrict__ poss_node)
{
  int tid = threadIdx.x;
  if (tid >= 255) return;                 // 15 nodes x 17 classes
  int g = tid / 17;
  int n = blockIdx.x * 15 + g;
  if (n >= NNODES) return;
  int c = tid - g * 17;

  u32 deg = min(cursor[n], (u32)BCAP);
  float ns = nsum[n];
  const uint2* bk = (const uint2*)bucket + (size_t)n * BCAP;

  float acc = 0.f;
  u32 k = 0;
  for (; k + 4 <= deg; k += 4) {
    uint2 b0 = bk[k], b1 = bk[k + 1], b2 = bk[k + 2], b3 = bk[k + 3];
    float p0 = poss_edge[(size_t)b0.x * NCLS + c];
    float p1 = poss_edge[(size_t)b1.x * NCLS + c];
    float p2 = poss_edge[(size_t)b2.x * NCLS + c];
    float p3 = poss_edge[(size_t)b3.x * NCLS + c];
    acc = fmaf(p0, __uint_as_float(b0.y), acc);
    acc = fmaf(p1, __uint_as_float(b1.y), acc);
    acc = fmaf(p2, __uint_as_float(b2.y), acc);
    acc = fmaf(p3, __uint_as_float(b3.y), acc);
  }
  for (; k < deg; ++k) {
    uint2 b = bk[k];
    acc = fmaf(poss_edge[(size_t)b.x * NCLS + c], __uint_as_float(b.y), acc);
  }

  size_t o = (size_t)n * NCLS + c;
  recall[o]    = acc;
  poss_node[o] = acc / ns;
}

// ---------------- Fallback divide ----------------
__global__ __launch_bounds__(256) void div_kernel(
    const float* __restrict__ recall,
    const float* __restrict__ nsum,
    float* __restrict__ poss_node)
{
  int i = blockIdx.x * 256 + threadIdx.x;
  if (i < NNODES * NCLS)
    poss_node[i] = recall[i] / nsum[i / NCLS];
}

extern "C" void kernel_launch(void* const* d_in, const int* in_sizes, int n_in,
                              void* d_out, int out_size, void* d_ws, size_t ws_size,
                              hipStream_t stream) {
  const float* features = (const float*)d_in[0];
  const int*   edges    = (const int*)d_in[1];
  const float* weights  = (const float*)d_in[2];
  const float* nsum     = (const float*)d_in[3];
  const float* W_embed  = (const float*)d_in[4];
  const float* b_embed  = (const float*)d_in[5];
  const float* W_trans  = (const float*)d_in[6];
  const float* b_trans  = (const float*)d_in[7];

  float* out       = (float*)d_out;
  float* poss_node = out;
  float* poss_edge = out + (size_t)NNODES * NCLS;
  float* recall    = out + (size_t)(NNODES + NEDGES) * NCLS;

  // workspace layout: nodetab | cursor | wpack | bucket
  u32* nodetab = (u32*)d_ws;                                  // 6.4 MB
  u32* cursor  = nodetab + (size_t)NNODES * ROWU;             // 0.4 MB
  u32* wpack   = cursor + NNODES;                             // 2.2 KB
  u32* bucket  = wpack + 2 * WPK;                             // 51.2 MB (uint2)
  size_t need_fast = ((size_t)NNODES * ROWU + NNODES + 2 * WPK
                     + (size_t)NNODES * BCAP * 2) * 4;        // ~58 MB
  size_t need_min  = ((size_t)NNODES * ROWU + NNODES + 2 * WPK) * 4;

  if (ws_size >= need_fast) {
    hipMemsetAsync(cursor, 0, (size_t)NNODES * sizeof(u32), stream);
    prep_kernel<<<1, 256, 0, stream>>>(W_trans, wpack);
    node_kernel<<<(NNODES + 63) / 64, 64, 0, stream>>>(features, W_embed, b_embed,
                                                       nodetab);
    edge_kernel4<1><<<NEDGES / 256, 256, 0, stream>>>(edges, weights, wpack, b_trans,
                                                      nodetab, poss_edge, cursor, bucket,
                                                      nullptr);
    reduce_kernel<<<(NNODES + 14) / 15, 256, 0, stream>>>(poss_edge, cursor, bucket,
                                                          nsum, recall, poss_node);
  } else if (ws_size >= need_min) {
    // fallback: fp32 atomic scatter + separate divide (no bucket space)
    hipMemsetAsync(recall, 0, (size_t)NNODES * NCLS * sizeof(float), stream);
    prep_kernel<<<1, 256, 0, stream>>>(W_trans, wpack);
    node_kernel<<<(NNODES + 63) / 64, 64, 0, stream>>>(features, W_embed, b_embed,
                                                       nodetab);
    edge_kernel4<0><<<NEDGES / 256, 256, 0, stream>>>(edges, weights, wpack, b_trans,
                                                      nodetab, poss_edge, nullptr, nullptr,
                                                      recall);
    div_kernel<<<(NNODES * NCLS + 255) / 256, 256, 0, stream>>>(recall, nsum, poss_node);
  }
}

// Round 5
// 372.373 us; speedup vs baseline: 1.3296x; 1.0009x over previous
//
#include <hip/hip_runtime.h>

#define NNODES 100000
#define NEDGES 1600000
#define FDIM 128
#define EDIM 32
#define NCLS 17
#define ROWU 16   // embed-only row: 16 u32 = 32 x f16 = 64 B = ONE cache line
#define BCAP 64   // bucket capacity per node; deg ~ Poisson(16), P(deg>=64) ~ 1e-18
#define WPK (16 * NCLS)   // packed half2 table entries per half (u- and v- tables)

typedef unsigned int u32;
typedef _Float16 h2 __attribute__((ext_vector_type(2)));

__device__ inline h2 bch(u32 x) { return __builtin_bit_cast(h2, x); }

// dot2: acc += a[0]*w[0] + a[1]*w[1], f32 accumulate
__device__ inline float dot2acc(h2 a, u32 wbits, float acc) {
#if __has_builtin(__builtin_amdgcn_fdot2)
  return __builtin_amdgcn_fdot2(a, bch(wbits), acc, false);
#else
  h2 w = bch(wbits);
  acc = fmaf((float)a[0], (float)w[0], acc);
  return fmaf((float)a[1], (float)w[1], acc);
#endif
}

// ---------------- Kernel P: pack W_trans into half2 tables ----------------
__global__ __launch_bounds__(256) void prep_kernel(
    const float* __restrict__ W_trans, u32* __restrict__ wpack)
{
  for (int x = threadIdx.x; x < 2 * WPK; x += 256) {
    int tab = x / WPK;
    int r   = x - tab * WPK;
    int k2  = r / NCLS, c = r - k2 * NCLS;
    int row0 = tab ? (EDIM + 2 * k2) : (2 * k2);
    float a = W_trans[row0 * NCLS + c];
    float b = W_trans[(row0 + 1) * NCLS + c];
    if (!tab) { a *= 0.5f; b *= 0.5f; }
    h2 p; p[0] = (_Float16)a; p[1] = (_Float16)b;
    wpack[x] = __builtin_bit_cast(u32, p);
  }
}

// ---------------- Kernel A: per-node embed only, 64-thread blocks ----------------
__global__ __launch_bounds__(64) void node_kernel(
    const float* __restrict__ features,
    const float* __restrict__ W_embed,   // [128][32]
    const float* __restrict__ b_embed,   // [32]
    u32* __restrict__ nodetab)
{
  int n = blockIdx.x * 64 + threadIdx.x;
  if (n >= NNODES) return;

  float acc[EDIM];
  #pragma unroll
  for (int c = 0; c < EDIM; ++c) acc[c] = b_embed[c];

  const float4* f4 = (const float4*)(features + (size_t)n * FDIM);
  for (int k4 = 0; k4 < FDIM / 4; ++k4) {
    float4 f = f4[k4];
    const float* w = W_embed + k4 * 4 * EDIM;   // uniform -> s_load
    #pragma unroll
    for (int c = 0; c < EDIM; ++c) {
      acc[c] = fmaf(f.x, w[c],            acc[c]);
      acc[c] = fmaf(f.y, w[EDIM + c],     acc[c]);
      acc[c] = fmaf(f.z, w[2 * EDIM + c], acc[c]);
      acc[c] = fmaf(f.w, w[3 * EDIM + c], acc[c]);
    }
  }

  u32 p[16];
  #pragma unroll
  for (int i = 0; i < 16; ++i) {
    h2 t; t[0] = (_Float16)acc[2 * i]; t[1] = (_Float16)acc[2 * i + 1];
    p[i] = __builtin_bit_cast(u32, t);
  }
  uint4* row = (uint4*)(nodetab + (size_t)n * ROWU);
  #pragma unroll
  for (int i = 0; i < 4; ++i)
    row[i] = make_uint4(p[4 * i], p[4 * i + 1], p[4 * i + 2], p[4 * i + 3]);
}

// ---------------- Kernel B: cooperative row gather -> LDS, then per-edge logits ----------------
// Gather: 512 rows (256 edges x {src,dst}) staged by quarter-rows: per instruction
// 4 lanes share one 64 B line -> TA coalesces to ONE line-request (512->128
// line-touches per wave vs per-lane gathers). Rows LDS is XOR-swizzled on the
// 16 B piece index to spread banks; after a barrier the same LDS is reused for
// the coalesced poss_edge staging.
// FAST=1: scatter uint2(eid, w) bucket entry. FAST=0: fp32 atomic scatter tail.
template <int FAST>
__global__ __launch_bounds__(256, 4) void edge_kernel5(
    const int*   __restrict__ edges,
    const float* __restrict__ weights,
    const u32*   __restrict__ wpack,     // 2*WPK packed half2 (uniform -> s_load)
    const float* __restrict__ b_trans,   // [17]
    const u32*   __restrict__ nodetab,
    float* __restrict__ poss_edge,
    u32*   __restrict__ cursor,          // FAST
    u32*   __restrict__ bucket,          // FAST (uint2 entries)
    float* __restrict__ recall)          // !FAST
{
  // sBuf[0..8191]    : 256 edge-rows x 32 u32 (src 4 pieces + dst 4 pieces, 16 B each,
  //                    piece index XOR-swizzled by (edge&7)); later reused as sOut
  // sBuf[8192..8703] : node ids (src[256], dst[256])
  __shared__ u32 sBuf[256 * 32 + 512];
  u32*   sIDs = sBuf + 256 * 32;
  float* sOut = (float*)sBuf;

  int tid = threadIdx.x;
  int e = blockIdx.x * 256 + tid;
  int2 ed = ((const int2*)edges)[e];
  int src = ed.x, dst = ed.y;
  float w = weights[e];

  sIDs[tid]       = (u32)src;
  sIDs[256 + tid] = (u32)dst;

  if (FAST) {
    // CSR-lite bucket insert, issued early to overlap the staging below
    u32 slot = atomicAdd(cursor + src, 1u);
    if (slot < BCAP)
      ((uint2*)bucket)[(size_t)src * BCAP + slot] =
          make_uint2((u32)e, __float_as_uint(w));
  }
  __syncthreads();

  // cooperative gather: 8 insts/thread, each loads one 16 B quarter-row.
  // piece id g = it*256+tid: edge t = g>>3, piece p = g&7 (p<4: src, else dst).
  #pragma unroll
  for (int it = 0; it < 8; ++it) {
    int g = it * 256 + tid;
    int t = g >> 3, p = g & 7;
    u32 node = sIDs[(p >> 2) * 256 + t];
    uint4 v = ((const uint4*)(nodetab + (size_t)node * ROWU))[p & 3];
    *((uint4*)(sBuf + t * 32 + ((p ^ (t & 7)) << 2))) = v;
  }
  __syncthreads();

  // per-edge: read own rows from LDS (swizzled), compute logits
  uint4 sq[4], dq[4];
  #pragma unroll
  for (int p = 0; p < 8; ++p) {
    uint4 v = *((const uint4*)(sBuf + tid * 32 + ((p ^ (tid & 7)) << 2)));
    if (p < 4) sq[p] = v; else dq[p - 4] = v;
  }

  float lgt[NCLS];
  #pragma unroll
  for (int c = 0; c < NCLS; ++c) lgt[c] = b_trans[c];

  #pragma unroll
  for (int q = 0; q < 4; ++q) {
    u32 su[4] = {sq[q].x, sq[q].y, sq[q].z, sq[q].w};
    u32 du[4] = {dq[q].x, dq[q].y, dq[q].z, dq[q].w};
    #pragma unroll
    for (int j = 0; j < 4; ++j) {
      int k2 = q * 4 + j;
      h2 s2 = bch(su[j]), d2 = bch(du[j]);
      h2 uu = s2 + d2;                 // v_pk_add_f16 (0.5 folded into W1 table)
      h2 t  = s2 - d2;
      h2 vv = t * t;                   // v_pk_mul_f16
      const u32* w1 = wpack + k2 * NCLS;         // uniform -> s_load
      const u32* w2 = wpack + WPK + k2 * NCLS;
      #pragma unroll
      for (int c = 0; c < NCLS; ++c) {
        lgt[c] = dot2acc(uu, w1[c], lgt[c]);
        lgt[c] = dot2acc(vv, w2[c], lgt[c]);
      }
    }
  }

  float m = lgt[0];
  #pragma unroll
  for (int c = 1; c < NCLS; ++c) m = fmaxf(m, lgt[c]);
  float sum = 0.f;
  #pragma unroll
  for (int c = 0; c < NCLS; ++c) { lgt[c] = __expf(lgt[c] - m); sum += lgt[c]; }
  float inv = 1.0f / sum;

  __syncthreads();   // all row reads done: rows area can be reused as sOut

  #pragma unroll
  for (int c = 0; c < NCLS; ++c) sOut[tid * NCLS + c] = lgt[c] * inv;
  __syncthreads();

  // coalesced float4 poss_edge store
  float4* outp = (float4*)(poss_edge + (size_t)blockIdx.x * 256 * NCLS);
  const float4* sOut4 = (const float4*)sOut;
  for (int i = tid; i < 256 * NCLS / 4; i += 256)
    outp[i] = sOut4[i];

  if (!FAST) {
    __syncthreads();
    float wi = w * inv;
    #pragma unroll
    for (int c = 0; c < NCLS; ++c) sOut[tid * NCLS + c] = lgt[c] * wi;
    __syncthreads();
    for (int i = tid; i < 256 * NCLS; i += 256) {
      unsigned e2 = (unsigned)i / NCLS;
      unsigned c2 = (unsigned)i - e2 * NCLS;
      atomicAdd(recall + (size_t)sIDs[e2] * NCLS + c2, sOut[i]);
    }
  }
}

// ---------------- Kernel R: gather segment-sum + fused divide, 4-deep MLP ----------------
__global__ __launch_bounds__(256, 8) void reduce_kernel(
    const float* __restrict__ poss_edge,
    const u32*   __restrict__ cursor,
    const u32*   __restrict__ bucket,    // uint2 entries (eid, weight_bits)
    const float* __restrict__ nsum,
    float* __restrict__ recall,
    float* __restrict__ poss_node)
{
  int tid = threadIdx.x;
  if (tid >= 255) return;                 // 15 nodes x 17 classes
  int g = tid / 17;
  int n = blockIdx.x * 15 + g;
  if (n >= NNODES) return;
  int c = tid - g * 17;

  u32 deg = min(cursor[n], (u32)BCAP);
  float ns = nsum[n];
  const uint2* bk = (const uint2*)bucket + (size_t)n * BCAP;

  float acc = 0.f;
  u32 k = 0;
  for (; k + 4 <= deg; k += 4) {
    uint2 b0 = bk[k], b1 = bk[k + 1], b2 = bk[k + 2], b3 = bk[k + 3];
    float p0 = poss_edge[(size_t)b0.x * NCLS + c];
    float p1 = poss_edge[(size_t)b1.x * NCLS + c];
    float p2 = poss_edge[(size_t)b2.x * NCLS + c];
    float p3 = poss_edge[(size_t)b3.x * NCLS + c];
    acc = fmaf(p0, __uint_as_float(b0.y), acc);
    acc = fmaf(p1, __uint_as_float(b1.y), acc);
    acc = fmaf(p2, __uint_as_float(b2.y), acc);
    acc = fmaf(p3, __uint_as_float(b3.y), acc);
  }
  for (; k < deg; ++k) {
    uint2 b = bk[k];
    acc = fmaf(poss_edge[(size_t)b.x * NCLS + c], __uint_as_float(b.y), acc);
  }

  size_t o = (size_t)n * NCLS + c;
  recall[o]    = acc;
  poss_node[o] = acc / ns;
}

// ---------------- Fallback divide ----------------
__global__ __launch_bounds__(256) void div_kernel(
    const float* __restrict__ recall,
    const float* __restrict__ nsum,
    float* __restrict__ poss_node)
{
  int i = blockIdx.x * 256 + threadIdx.x;
  if (i < NNODES * NCLS)
    poss_node[i] = recall[i] / nsum[i / NCLS];
}

extern "C" void kernel_launch(void* const* d_in, const int* in_sizes, int n_in,
                              void* d_out, int out_size, void* d_ws, size_t ws_size,
                              hipStream_t stream) {
  const float* features = (const float*)d_in[0];
  const int*   edges    = (const int*)d_in[1];
  const float* weights  = (const float*)d_in[2];
  const float* nsum     = (const float*)d_in[3];
  const float* W_embed  = (const float*)d_in[4];
  const float* b_embed  = (const float*)d_in[5];
  const float* W_trans  = (const float*)d_in[6];
  const float* b_trans  = (const float*)d_in[7];

  float* out       = (float*)d_out;
  float* poss_node = out;
  float* poss_edge = out + (size_t)NNODES * NCLS;
  float* recall    = out + (size_t)(NNODES + NEDGES) * NCLS;

  // workspace layout: nodetab | cursor | wpack | bucket
  u32* nodetab = (u32*)d_ws;                                  // 6.4 MB
  u32* cursor  = nodetab + (size_t)NNODES * ROWU;             // 0.4 MB
  u32* wpack   = cursor + NNODES;                             // 2.2 KB
  u32* bucket  = wpack + 2 * WPK;                             // 51.2 MB (uint2)
  size_t need_fast = ((size_t)NNODES * ROWU + NNODES + 2 * WPK
                     + (size_t)NNODES * BCAP * 2) * 4;        // ~58 MB
  size_t need_min  = ((size_t)NNODES * ROWU + NNODES + 2 * WPK) * 4;

  if (ws_size >= need_fast) {
    hipMemsetAsync(cursor, 0, (size_t)NNODES * sizeof(u32), stream);
    prep_kernel<<<1, 256, 0, stream>>>(W_trans, wpack);
    node_kernel<<<(NNODES + 63) / 64, 64, 0, stream>>>(features, W_embed, b_embed,
                                                       nodetab);
    edge_kernel5<1><<<NEDGES / 256, 256, 0, stream>>>(edges, weights, wpack, b_trans,
                                                      nodetab, poss_edge, cursor, bucket,
                                                      nullptr);
    reduce_kernel<<<(NNODES + 14) / 15, 256, 0, stream>>>(poss_edge, cursor, bucket,
                                                          nsum, recall, poss_node);
  } else if (ws_size >= need_min) {
    // fallback: fp32 atomic scatter + separate divide (no bucket space)
    hipMemsetAsync(recall, 0, (size_t)NNODES * NCLS * sizeof(float), stream);
    prep_kernel<<<1, 256, 0, stream>>>(W_trans, wpack);
    node_kernel<<<(NNODES + 63) / 64, 64, 0, stream>>>(features, W_embed, b_embed,
                                                       nodetab);
    edge_kernel5<0><<<NEDGES / 256, 256, 0, stream>>>(edges, weights, wpack, b_trans,
                                                      nodetab, poss_edge, nullptr, nullptr,
                                                      recall);
    div_kernel<<<(NNODES * NCLS + 255) / 256, 256, 0, stream>>>(recall, nsum, poss_node);
  }
}